// Round 3
// baseline (295.201 us; speedup 1.0000x reference)
//
#include <hip/hip_runtime.h>
#include <hip/hip_bf16.h>
#include <math.h>

// Problem constants
#define BB 4
#define TT 2048
#define CC 1024
#define HH 16
#define DD 64
#define WW 256
#define MM (BB*TT)   // 8192 rows
#define NX (MM*CC)
#define NQ (3*CC*CC)
#define NP (CC*CC)

typedef __bf16 bf16x8 __attribute__((ext_vector_type(8)));
typedef __bf16 bf16x4 __attribute__((ext_vector_type(4)));
typedef float  f32x4  __attribute__((ext_vector_type(4)));

// async global->LDS 16B: LDS dest is wave-uniform base; HW adds lane*16
__device__ __forceinline__ void async_cp16(const void* g, void* l) {
  __builtin_amdgcn_global_load_lds(
      (const __attribute__((address_space(1))) void*)g,
      (__attribute__((address_space(3))) void*)l, 16, 0, 0);
}

__device__ __forceinline__ unsigned short f2bf(float v) {
  __hip_bfloat16 h = __float2bfloat16(v);
  return *(unsigned short*)&h;
}

// ---------------------------------------------------------------------------
// fused fp32 -> bf16 conversion of x, Wqkv, Wproj (dsts contiguous in ws)
// ---------------------------------------------------------------------------
__global__ void convert3(const float* __restrict__ x,
                         const float* __restrict__ wq,
                         const float* __restrict__ wp,
                         __hip_bfloat16* __restrict__ dst) {
  int i = (blockIdx.x * 256 + threadIdx.x) * 4;
  const float* src; int off;
  if (i < NX)           { src = x;  off = i; }
  else if (i < NX + NQ) { src = wq; off = i - NX; }
  else                  { src = wp; off = i - NX - NQ; }
  float4 v = *(const float4*)(src + off);
  dst[i + 0] = __float2bfloat16(v.x);
  dst[i + 1] = __float2bfloat16(v.y);
  dst[i + 2] = __float2bfloat16(v.z);
  dst[i + 3] = __float2bfloat16(v.w);
}

// ---------------------------------------------------------------------------
// GEMM: C = A[M,K] * W[N,K]^T, bf16 in, fp32 acc. 128x128 tile, BK=64.
// True LDS double-buffer: stage(k+1) -> compute(k) -> ONE barrier, so the
// global_load_lds latency overlaps the MFMA burst instead of being drained
// cold at a pre-compute barrier. Distinct __shared__ arrays per buffer give
// static no-alias between DMA writes and ds_reads.
// MODE 0: fp32 output row-major.
// MODE 1: qkv scatter -> Qh/Kh/Vh [b*h][t][d] bf16, Q pre-scaled by 0.125.
// ---------------------------------------------------------------------------
template<int MODE>
__global__ __launch_bounds__(256, 2)
void gemm_bt(const unsigned short* __restrict__ A,
             const unsigned short* __restrict__ Bw,
             void* __restrict__ Co, int M, int N, int K,
             unsigned short* __restrict__ Qh,
             unsigned short* __restrict__ Kh,
             unsigned short* __restrict__ Vh) {
  __shared__ __align__(16) unsigned short As0[8 * 1024]; // [kc][128 rows][8]
  __shared__ __align__(16) unsigned short Bs0[8 * 1024];
  __shared__ __align__(16) unsigned short As1[8 * 1024];
  __shared__ __align__(16) unsigned short Bs1[8 * 1024];

  const int tid  = threadIdx.x;
  const int w    = tid >> 6;
  const int lane = tid & 63;
  const int quad = lane >> 4;
  const int l15  = lane & 15;
  const int m0 = blockIdx.x * 128;
  const int n0 = blockIdx.y * 128;
  const int wm = w & 1;
  const int wn = w >> 1;

  f32x4 acc[4][4];
#pragma unroll
  for (int i = 0; i < 4; i++)
#pragma unroll
    for (int j = 0; j < 4; j++) acc[i][j] = (f32x4)0.0f;

  auto stage = [&](int k0, unsigned short* as, unsigned short* bs) {
#pragma unroll
    for (int i = 0; i < 4; i++) {
      int idx = w + 4 * i;
      int kc  = idx >> 1;
      int mh  = idx & 1;
      async_cp16(A + (size_t)(m0 + mh * 64 + lane) * K + (k0 + kc * 8),
                 &as[kc * 1024 + mh * 512]);
      async_cp16(Bw + (size_t)(n0 + mh * 64 + lane) * K + (k0 + kc * 8),
                 &bs[kc * 1024 + mh * 512]);
    }
  };
  auto compute = [&](const unsigned short* as, const unsigned short* bs) {
#pragma unroll
    for (int ks = 0; ks < 2; ks++) {
      bf16x8 af[4], bfv[4];
      int kc = ks * 4 + quad;
#pragma unroll
      for (int t = 0; t < 4; t++) {
        af[t]  = *(const bf16x8*)&as[kc * 1024 + (wm * 64 + t * 16 + l15) * 8];
        bfv[t] = *(const bf16x8*)&bs[kc * 1024 + (wn * 64 + t * 16 + l15) * 8];
      }
#pragma unroll
      for (int tm = 0; tm < 4; tm++)
#pragma unroll
        for (int tn = 0; tn < 4; tn++)
          acc[tm][tn] = __builtin_amdgcn_mfma_f32_16x16x32_bf16(
              af[tm], bfv[tn], acc[tm][tn], 0, 0, 0);
    }
  };

  stage(0, As0, Bs0);
  __syncthreads();
  for (int k0 = 0; k0 < K; k0 += 128) {
    stage(k0 + 64, As1, Bs1);          // prefetch odd tile
    compute(As0, Bs0);                 // overlaps with prefetch latency
    __syncthreads();                   // drains vmcnt: odd tile now visible
    if (k0 + 128 < K) stage(k0 + 128, As0, Bs0);
    compute(As1, Bs1);
    __syncthreads();
  }

  if (MODE == 0) {
#pragma unroll
    for (int tm = 0; tm < 4; tm++)
#pragma unroll
      for (int tn = 0; tn < 4; tn++)
#pragma unroll
        for (int r = 0; r < 4; r++) {
          int row = m0 + wm * 64 + tm * 16 + quad * 4 + r;
          int col = n0 + wn * 64 + tn * 16 + l15;
          ((float*)Co)[(size_t)row * N + col] = acc[tm][tn][r];
        }
  } else {
    // scatter qkv: col -> (which, head, d); row -> (b, t)
#pragma unroll
    for (int tm = 0; tm < 4; tm++)
#pragma unroll
      for (int tn = 0; tn < 4; tn++) {
        int colb = n0 + wn * 64 + tn * 16;     // 16-aligned: t3,h uniform
        int t3 = colb >> 10;
        int hh = (colb >> 6) & 15;
        int dd = (colb & 63) + l15;
        unsigned short* dst = (t3 == 0) ? Qh : ((t3 == 1) ? Kh : Vh);
        float sc = (t3 == 0) ? 0.125f : 1.0f;  // 1/sqrt(64), exact
#pragma unroll
        for (int r = 0; r < 4; r++) {
          int row = m0 + wm * 64 + tm * 16 + quad * 4 + r;
          int b = row >> 11, tt = row & 2047;
          dst[((size_t)((b * 16 + hh) * 2048 + tt)) * 64 + dd] =
              f2bf(acc[tm][tn][r] * sc);
        }
      }
  }
}

// ---------------------------------------------------------------------------
// Vh [bh][t][d] -> Vt chunk-blocked [bh][tc=32][d=64][tin=64]
// ---------------------------------------------------------------------------
__global__ __launch_bounds__(256)
void transpose_v(const unsigned short* __restrict__ Vh,
                 unsigned short* __restrict__ Vt) {
  __shared__ __align__(16) unsigned short tile[64 * 72]; // row stride 144B
  const int tid = threadIdx.x;
  const int tc = blockIdx.x, bh = blockIdx.y;
  const unsigned short* src = Vh + ((size_t)bh * 2048 + (size_t)tc * 64) * 64;
  for (int i = tid; i < 512; i += 256) {
    int r = i >> 3, ds = (i & 7) * 8;
    *(uint4*)&tile[r * 72 + ds] = *(const uint4*)&src[(size_t)r * 64 + ds];
  }
  __syncthreads();
  unsigned short* dst = Vt + (size_t)(bh * 32 + tc) * 4096;
  for (int i = tid; i < 512; i += 256) {
    int d = i >> 3, ts = (i & 7) * 8;
    unsigned int w0 = tile[(ts + 0) * 72 + d] | ((unsigned int)tile[(ts + 1) * 72 + d] << 16);
    unsigned int w1 = tile[(ts + 2) * 72 + d] | ((unsigned int)tile[(ts + 3) * 72 + d] << 16);
    unsigned int w2 = tile[(ts + 4) * 72 + d] | ((unsigned int)tile[(ts + 5) * 72 + d] << 16);
    unsigned int w3 = tile[(ts + 6) * 72 + d] | ((unsigned int)tile[(ts + 7) * 72 + d] << 16);
    uint4 o; o.x = w0; o.y = w1; o.z = w2; o.w = w3;
    *(uint4*)&dst[(size_t)d * 64 + ts] = o;
  }
}

// ---------------------------------------------------------------------------
// MFMA sliding-window flash attention (unchanged from round 2).
// ---------------------------------------------------------------------------
__global__ __launch_bounds__(256, 2)
void attn_mfma(const unsigned short* __restrict__ Qh,
               const unsigned short* __restrict__ Kh,
               const unsigned short* __restrict__ Vt,
               __hip_bfloat16* __restrict__ y) {
  __shared__ __align__(16) unsigned short Qs[8 * 512]; // [kc_d][q 64][8]
  __shared__ __align__(16) unsigned short Ks[8 * 512]; // [kc_d][j 64][8]
  __shared__ __align__(16) unsigned short Vs[8 * 512]; // [kc_j][d 64][8]
  __shared__ __align__(16) unsigned short Ps[64 * 68]; // [q][j], row 136B

  const int tid  = threadIdx.x;
  const int w    = tid >> 6;
  const int lane = tid & 63;
  const int quad = lane >> 4;
  const int l15  = lane & 15;
  const int q0 = blockIdx.x * 64;
  const int bh = blockIdx.y;            // b*16+h

  const unsigned short* Qg = Qh + ((size_t)bh * 2048 + q0) * 64;

#pragma unroll
  for (int i = 0; i < 2; i++) {
    int kc = w * 2 + i;
    async_cp16(Qg + (size_t)lane * 64 + kc * 8, &Qs[kc * 512]);
  }

  f32x4 Oacc[4];
  float m_[4], l_[4];
#pragma unroll
  for (int t = 0; t < 4; t++) { Oacc[t] = (f32x4)0.0f; }
#pragma unroll
  for (int r = 0; r < 4; r++) { m_[r] = -__builtin_inff(); l_[r] = 0.0f; }

  for (int c = 0; c < 5; c++) {
    const int sc = q0 - 256 + c * 64;   // block-uniform
    if (sc < 0) continue;
    __syncthreads();                    // prior chunk's Ks/Vs reads complete
    const unsigned short* Kg = Kh + ((size_t)bh * 2048 + sc) * 64;
    const unsigned short* Vg = Vt + ((size_t)(bh * 32) + (sc >> 6)) * 4096;
#pragma unroll
    for (int i = 0; i < 2; i++) {
      int kc = w * 2 + i;
      async_cp16(Kg + (size_t)lane * 64 + kc * 8, &Ks[kc * 512]);
      async_cp16(Vg + (size_t)lane * 64 + kc * 8, &Vs[kc * 512]);
    }
    __syncthreads();                    // drains vmcnt -> staging visible

    // ---- S = Q K^T
    f32x4 S[4];
#pragma unroll
    for (int tn = 0; tn < 4; tn++) S[tn] = (f32x4)0.0f;
#pragma unroll
    for (int ks = 0; ks < 2; ks++) {
      int kc = ks * 4 + quad;
      bf16x8 aq = *(const bf16x8*)&Qs[kc * 512 + (w * 16 + l15) * 8];
#pragma unroll
      for (int tn = 0; tn < 4; tn++) {
        bf16x8 bk = *(const bf16x8*)&Ks[kc * 512 + (tn * 16 + l15) * 8];
        S[tn] = __builtin_amdgcn_mfma_f32_16x16x32_bf16(aq, bk, S[tn], 0, 0, 0);
      }
    }

    // ---- mask (only first/last chunk partial)
    const int qb = q0 + w * 16 + quad * 4;  // + r
    if (c == 0) {
#pragma unroll
      for (int tn = 0; tn < 4; tn++) {
        int j = sc + tn * 16 + l15;
#pragma unroll
        for (int r = 0; r < 4; r++)
          if (qb + r > j + (WW - 1)) S[tn][r] = -__builtin_inff();
      }
    } else if (sc == q0) {
#pragma unroll
      for (int tn = 0; tn < 4; tn++) {
        int j = sc + tn * 16 + l15;
#pragma unroll
        for (int r = 0; r < 4; r++)
          if (j > qb + r) S[tn][r] = -__builtin_inff();
      }
    }

    // ---- online softmax
    float mx[4], al[4], em[4], ps[4];
#pragma unroll
    for (int r = 0; r < 4; r++)
      mx[r] = fmaxf(fmaxf(S[0][r], S[1][r]), fmaxf(S[2][r], S[3][r]));
#pragma unroll
    for (int off = 1; off < 16; off <<= 1)
#pragma unroll
      for (int r = 0; r < 4; r++) mx[r] = fmaxf(mx[r], __shfl_xor(mx[r], off));
#pragma unroll
    for (int r = 0; r < 4; r++) {
      float mn = fmaxf(m_[r], mx[r]);
      em[r] = (mn == -__builtin_inff()) ? 0.0f : mn;
      al[r] = __expf(m_[r] - em[r]);
      m_[r] = mn;
    }
#pragma unroll
    for (int tn = 0; tn < 4; tn++)
#pragma unroll
      for (int r = 0; r < 4; r++)
        S[tn][r] = __expf(S[tn][r] - em[r]);
#pragma unroll
    for (int r = 0; r < 4; r++)
      ps[r] = (S[0][r] + S[1][r]) + (S[2][r] + S[3][r]);
#pragma unroll
    for (int off = 1; off < 16; off <<= 1)
#pragma unroll
      for (int r = 0; r < 4; r++) ps[r] += __shfl_xor(ps[r], off);
#pragma unroll
    for (int r = 0; r < 4; r++) l_[r] = l_[r] * al[r] + ps[r];

#pragma unroll
    for (int td = 0; td < 4; td++)
#pragma unroll
      for (int r = 0; r < 4; r++) Oacc[td][r] *= al[r];

    // ---- P -> LDS (bf16)
#pragma unroll
    for (int tn = 0; tn < 4; tn++)
#pragma unroll
      for (int r = 0; r < 4; r++)
        Ps[(w * 16 + quad * 4 + r) * 68 + tn * 16 + l15] = f2bf(S[tn][r]);
    asm volatile("s_waitcnt lgkmcnt(0)" ::: "memory");

    // ---- O += P V
#pragma unroll
    for (int ks = 0; ks < 2; ks++) {
      int off = (w * 16 + l15) * 68 + ks * 32 + quad * 8;
      bf16x4 plo = *(const bf16x4*)&Ps[off];
      bf16x4 phi = *(const bf16x4*)&Ps[off + 4];
      bf16x8 ap = __builtin_shufflevector(plo, phi, 0, 1, 2, 3, 4, 5, 6, 7);
      int kc = ks * 4 + quad;
#pragma unroll
      for (int td = 0; td < 4; td++) {
        bf16x8 bv = *(const bf16x8*)&Vs[kc * 512 + (td * 16 + l15) * 8];
        Oacc[td] = __builtin_amdgcn_mfma_f32_16x16x32_bf16(ap, bv, Oacc[td], 0, 0, 0);
      }
    }
  }

  // ---- epilogue
  const int b = bh >> 4, h = bh & 15;
  float inv[4];
#pragma unroll
  for (int r = 0; r < 4; r++) inv[r] = 1.0f / l_[r];
#pragma unroll
  for (int td = 0; td < 4; td++)
#pragma unroll
    for (int r = 0; r < 4; r++) {
      int q = q0 + w * 16 + quad * 4 + r;
      y[((size_t)(b * 2048 + q)) * 1024 + h * 64 + td * 16 + l15] =
          __float2bfloat16(Oacc[td][r] * inv[r]);
    }
}

// ---------------------------------------------------------------------------
extern "C" void kernel_launch(void* const* d_in, const int* in_sizes, int n_in,
                              void* d_out, int out_size, void* d_ws, size_t ws_size,
                              hipStream_t stream) {
  const float* x     = (const float*)d_in[0];
  const float* wqkv  = (const float*)d_in[1];
  const float* wproj = (const float*)d_in[2];
  float* out = (float*)d_out;

  char* ws = (char*)d_ws;
  // [0,16M)   xb (dead after QKV gemm) -> reused as Vt
  // [16,22M)  Wqkv bf16   [22,24M) Wproj bf16   (contiguous with xb for convert3)
  // [24,40M)  Qh   [40,56M) Kh   [56,72M) Vh   [72,88M) y bf16
  unsigned short* xb     = (unsigned short*)(ws);
  unsigned short* vtb    = (unsigned short*)(ws);  // aliases xb (after gemm)
  unsigned short* wqkvb  = (unsigned short*)(ws + (size_t)16 * 1024 * 1024);
  unsigned short* wprojb = (unsigned short*)(ws + (size_t)22 * 1024 * 1024);
  unsigned short* qh     = (unsigned short*)(ws + (size_t)24 * 1024 * 1024);
  unsigned short* kh     = (unsigned short*)(ws + (size_t)40 * 1024 * 1024);
  unsigned short* vh     = (unsigned short*)(ws + (size_t)56 * 1024 * 1024);
  unsigned short* yb     = (unsigned short*)(ws + (size_t)72 * 1024 * 1024);

  convert3<<<(NX + NQ + NP) / 1024, 256, 0, stream>>>(
      x, wqkv, wproj, (__hip_bfloat16*)xb);

  // qkv = x @ Wqkv^T, scattered to head-major Q/K/V (Q pre-scaled)
  gemm_bt<1><<<dim3(MM / 128, (3 * CC) / 128), 256, 0, stream>>>(
      xb, wqkvb, nullptr, MM, 3 * CC, CC, qh, kh, vh);

  // V -> chunk-blocked transpose (into xb region, now dead)
  transpose_v<<<dim3(32, 64), 256, 0, stream>>>(vh, vtb);

  // attention
  attn_mfma<<<dim3(TT / 64, BB * HH), 256, 0, stream>>>(
      qh, kh, vtb, (__hip_bfloat16*)yb);

  // out = y @ Wproj^T -> fp32
  gemm_bt<0><<<dim3(MM / 128, CC / 128), 256, 0, stream>>>(
      yb, wprojb, (void*)out, MM, CC, CC, nullptr, nullptr, nullptr);
}